// Round 1
// baseline (541.594 us; speedup 1.0000x reference)
//
#include <hip/hip_runtime.h>
#include <math.h>

// Problem constants
#define BB 2
#define RR 4096
#define NRAY (BB*RR)            // 8192
#define SC 48
#define NSAMP (NRAY*SC)         // 393216
#define CF 32
#define HID 64
#define ODIM 33                 // 1 sigma + 32 rgb
#define PRES 256
#define PLANE_HW (PRES*PRES)    // 65536
#define RAY_START 0.1f
#define RAY_END 2.0f
#define DELTA ((RAY_END-RAY_START)/(SC-1))

// workspace layout (in floats)
#define OFF_PLANEST  ((size_t)0)                        // 2*3*65536*32 = 12582912
#define OFF_DEPTH_C  ((size_t)12582912)                 // 393216
#define OFF_SIGMA_C  (OFF_DEPTH_C + 393216)             // 393216
#define OFF_RGB_C    (OFF_SIGMA_C + 393216)             // 12582912
#define OFF_DEPTH_F  (OFF_RGB_C + 12582912)             // 393216
#define OFF_SIGMA_F  (OFF_DEPTH_F + 393216)             // 393216
#define OFF_RGB_F    (OFF_SIGMA_F + 393216)             // 12582912
#define OFF_MINMAX   (OFF_RGB_F + 12582912)             // 2 uints
// total = 39321602 floats = 157.3 MB

__device__ __forceinline__ float softplusf(float x) {
    // jax.nn.softplus = logaddexp(x, 0) = max(x,0) + log1p(exp(-|x|))
    return fmaxf(x, 0.f) + log1pf(expf(-fabsf(x)));
}

// ---------------------------------------------------------------------------
// Kernel 1: transpose planes (B,3,C,H,W) -> (B,3,H,W,C) so a bilinear tap is
// one contiguous 128B read.
// grid: 6 (b*p) * 256 (y) * 4 (x tiles of 64) = 6144 blocks, 256 threads
__global__ __launch_bounds__(256) void transpose_planes(
    const float* __restrict__ in, float* __restrict__ out)
{
    __shared__ float tile[32][65];
    int bid = blockIdx.x;
    int xt = bid & 3;
    int y  = (bid >> 2) & 255;
    int pp = bid >> 10;          // b*3+p in [0,6)
    int tx = threadIdx.x & 63;
    int tc = threadIdx.x >> 6;   // 0..3
    const float* src = in + (size_t)pp * 32 * PLANE_HW + (size_t)y * PRES + (size_t)xt * 64;
    #pragma unroll
    for (int i = 0; i < 8; ++i) {
        int c = i * 4 + tc;
        tile[c][tx] = src[(size_t)c * PLANE_HW + tx];
    }
    __syncthreads();
    float* dst = out + ((size_t)pp * PLANE_HW + (size_t)y * PRES + (size_t)xt * 64) * 32;
    int c2 = threadIdx.x & 31;
    int x2 = threadIdx.x >> 5;   // 0..7
    #pragma unroll
    for (int i = 0; i < 8; ++i) {
        int x = i * 8 + x2;
        dst[(size_t)x * 32 + c2] = tile[c2][x];
    }
}

// ---------------------------------------------------------------------------
// Kernel 2: coarse depths = linspace(0.1,2.0,48) + noise*delta
__global__ __launch_bounds__(256) void coarse_depths(
    const float* __restrict__ noise, float* __restrict__ depth_c)
{
    int gid = blockIdx.x * 256 + threadIdx.x;   // exactly NSAMP threads
    int s = gid % SC;
    depth_c[gid] = RAY_START + (float)s * DELTA + noise[gid] * DELTA;
}

// ---------------------------------------------------------------------------
// Kernel 3: sample tri-planes + MLP for one depth array (shared by both passes)
// one thread per sample; weights cached in LDS
__global__ __launch_bounds__(256) void sample_mlp(
    const float* __restrict__ planesT,
    const float* __restrict__ depths,
    const float* __restrict__ origins,
    const float* __restrict__ dirs,
    const float* __restrict__ w1, const float* __restrict__ b1,
    const float* __restrict__ w2, const float* __restrict__ b2,
    float* __restrict__ sigma_out, float* __restrict__ rgb_out)
{
    __shared__ float sw1[CF * HID];
    __shared__ float sw2[HID * ODIM];
    __shared__ float sb1[HID];
    __shared__ float sb2[ODIM];
    for (int i = threadIdx.x; i < CF * HID; i += 256) sw1[i] = w1[i];
    for (int i = threadIdx.x; i < HID * ODIM; i += 256) sw2[i] = w2[i];
    if (threadIdx.x < HID) sb1[threadIdx.x] = b1[threadIdx.x];
    if (threadIdx.x < ODIM) sb2[threadIdx.x] = b2[threadIdx.x];
    __syncthreads();

    int gid = blockIdx.x * 256 + threadIdx.x;   // exactly NSAMP threads
    int ray = gid / SC;
    int b = ray >> 12;                          // ray / 4096
    float depth = depths[gid];
    float ox = origins[ray*3+0], oy = origins[ray*3+1], oz = origins[ray*3+2];
    float dx = dirs[ray*3+0],    dy = dirs[ray*3+1],    dz = dirs[ray*3+2];
    float cx = (ox + depth*dx) * 0.5f;   // coords * (2/BOX_WARP)
    float cy = (oy + depth*dy) * 0.5f;
    float cz = (oz + depth*dz) * 0.5f;

    float4 feat[8];
    #pragma unroll
    for (int q = 0; q < 8; ++q) feat[q] = make_float4(0.f, 0.f, 0.f, 0.f);

    float gxs[3] = {cx, cy, cz};
    float gys[3] = {cy, cz, cx};
    #pragma unroll
    for (int p = 0; p < 3; ++p) {
        float x = gxs[p] * 128.f + 127.5f;   // ((g+1)*256-1)*0.5
        float y = gys[p] * 128.f + 127.5f;
        float x0f = floorf(x), y0f = floorf(y);
        float wx1 = x - x0f, wy1 = y - y0f;
        int x0 = (int)x0f, y0 = (int)y0f;
        const float4* base = (const float4*)(planesT + (size_t)(b*3+p) * PLANE_HW * 32);
        #pragma unroll
        for (int dyi = 0; dyi < 2; ++dyi) {
            int yi = y0 + dyi;
            if (yi < 0 || yi > 255) continue;
            float wy = dyi ? wy1 : (1.f - wy1);
            #pragma unroll
            for (int dxi = 0; dxi < 2; ++dxi) {
                int xi = x0 + dxi;
                if (xi < 0 || xi > 255) continue;
                float w = wy * (dxi ? wx1 : (1.f - wx1));
                const float4* tp = base + ((size_t)(yi << 8) + xi) * 8;
                #pragma unroll
                for (int q = 0; q < 8; ++q) {
                    float4 v = tp[q];
                    feat[q].x = fmaf(w, v.x, feat[q].x);
                    feat[q].y = fmaf(w, v.y, feat[q].y);
                    feat[q].z = fmaf(w, v.z, feat[q].z);
                    feat[q].w = fmaf(w, v.w, feat[q].w);
                }
            }
        }
    }
    // mean over 3 planes
    const float inv3 = 1.f / 3.f;
    float f[CF];
    #pragma unroll
    for (int q = 0; q < 8; ++q) {
        f[q*4+0] = feat[q].x * inv3;
        f[q*4+1] = feat[q].y * inv3;
        f[q*4+2] = feat[q].z * inv3;
        f[q*4+3] = feat[q].w * inv3;
    }

    float o[ODIM];
    #pragma unroll
    for (int k = 0; k < ODIM; ++k) o[k] = sb2[k];
    #pragma unroll 4
    for (int j = 0; j < HID; ++j) {
        float h = sb1[j];
        #pragma unroll
        for (int i = 0; i < CF; ++i) h = fmaf(f[i], sw1[i*HID + j], h);
        h = softplusf(h);
        #pragma unroll
        for (int k = 0; k < ODIM; ++k) o[k] = fmaf(h, sw2[j*ODIM + k], o[k]);
    }
    sigma_out[gid] = o[0];
    float4* ro = (float4*)(rgb_out + (size_t)gid * 32);
    #pragma unroll
    for (int q = 0; q < 8; ++q) {
        float4 v;
        v.x = 1.002f / (1.f + expf(-o[q*4+1])) - 0.001f;
        v.y = 1.002f / (1.f + expf(-o[q*4+2])) - 0.001f;
        v.z = 1.002f / (1.f + expf(-o[q*4+3])) - 0.001f;
        v.w = 1.002f / (1.f + expf(-o[q*4+4])) - 0.001f;
        ro[q] = v;
    }
}

// ---------------------------------------------------------------------------
// Kernel 4: per-ray coarse ray-march -> weights -> inverse-CDF importance
// sampling; also global depth min/max via uint atomics (positive floats).
__global__ __launch_bounds__(64) void importance_kernel(
    const float* __restrict__ depth_c, const float* __restrict__ sigma_c,
    const float* __restrict__ noise_imp, float* __restrict__ depth_f,
    unsigned int* __restrict__ minmax)
{
    __shared__ float s_w[64][SC-1];     // 47
    __shared__ float s_bins[64][SC-1];  // 47
    __shared__ float s_cdf[64][SC-2];   // 46
    int tid = threadIdx.x;
    int ray = blockIdx.x * 64 + tid;
    float* w    = s_w[tid];
    float* bins = s_bins[tid];
    float* cdf  = s_cdf[tid];

    const float* d  = depth_c + (size_t)ray * SC;
    const float* sg = sigma_c + (size_t)ray * SC;
    float d0 = d[0];
    float dprev = d0, sprev = sg[0];
    float T = 1.f;
    for (int i = 0; i < SC-1; ++i) {
        float d1 = d[i+1], s1 = sg[i+1];
        bins[i] = 0.5f * (dprev + d1);
        float dens = softplusf(0.5f * (sprev + s1) - 1.f);
        float a = 1.f - expf(-dens * (d1 - dprev));
        w[i] = a * T;
        T *= 1.f - a + 1e-10f;
        dprev = d1; sprev = s1;
    }
    // wn[i] = 0.5*(max(w[i-1],w[i]) + max(w[i],w[i+1])) + 0.01, i=1..45; +1e-5 eps
    float sum = 0.f;
    for (int i = 1; i <= 45; ++i) {
        float wn = 0.5f * (fmaxf(w[i-1], w[i]) + fmaxf(w[i], w[i+1])) + 0.01f + 1e-5f;
        cdf[i] = wn;
        sum += wn;
    }
    cdf[0] = 0.f;
    float cum = 0.f;
    for (int i = 1; i <= 45; ++i) { cum += cdf[i] / sum; cdf[i] = cum; }

    float fmn = 1e30f, fmx = -1e30f;
    const float* u_row = noise_imp + (size_t)ray * SC;
    float* df_row = depth_f + (size_t)ray * SC;
    for (int j = 0; j < SC; ++j) {
        float u = u_row[j];
        int inds = 0;
        for (int t = 0; t < 46; ++t) inds += (cdf[t] <= u) ? 1 : 0;   // searchsorted right
        int below = inds - 1; if (below < 0) below = 0;
        int above = inds;     if (above > 45) above = 45;
        float cb = cdf[below], ca = cdf[above];
        float bb = bins[below], ba = bins[above];
        float den = (ca - cb) < 1e-5f ? 1.f : (ca - cb);
        float s = bb + (u - cb) / den * (ba - bb);
        df_row[j] = s;
        fmn = fminf(fmn, s); fmx = fmaxf(fmx, s);
    }
    fmn = fminf(fmn, d0);
    fmx = fmaxf(fmx, dprev);   // dprev == d[47]
    atomicMin(minmax + 0, __float_as_uint(fmn));
    atomicMax(minmax + 1, __float_as_uint(fmx));
}

// ---------------------------------------------------------------------------
// Kernel 5: merge coarse+fine (stable rank sort of 96), final ray-march,
// outputs. One wave per ray, 4 rays per block.
__global__ __launch_bounds__(256) void final_march(
    const float* __restrict__ depth_c, const float* __restrict__ sigma_c,
    const float* __restrict__ rgb_c,
    const float* __restrict__ depth_f, const float* __restrict__ sigma_f,
    const float* __restrict__ rgb_f,
    const unsigned int* __restrict__ minmax,
    float* __restrict__ out)
{
    __shared__ float dall[4][96];
    __shared__ float sall[4][96];
    __shared__ float dsrt[4][96];
    __shared__ float ssrt[4][96];
    __shared__ int   perm[4][96];
    __shared__ float al[4][96];    // alpha, then overwritten with weights

    int wid = threadIdx.x >> 6, lane = threadIdx.x & 63;
    int ray = blockIdx.x * 4 + wid;

    for (int j = lane; j < 96; j += 64) {
        float dv, sv;
        if (j < 48) { dv = depth_c[(size_t)ray*48 + j]; sv = sigma_c[(size_t)ray*48 + j]; }
        else        { dv = depth_f[(size_t)ray*48 + j-48]; sv = sigma_f[(size_t)ray*48 + j-48]; }
        dall[wid][j] = dv; sall[wid][j] = sv;
    }
    __syncthreads();
    // stable rank sort (ties broken by original concat index -> matches stable argsort)
    for (int j = lane; j < 96; j += 64) {
        float dj = dall[wid][j];
        int rank = 0;
        for (int k = 0; k < 96; ++k) {
            float dk = dall[wid][k];
            rank += (dk < dj || (dk == dj && k < j)) ? 1 : 0;
        }
        dsrt[wid][rank] = dj;
        ssrt[wid][rank] = sall[wid][j];
        perm[wid][rank] = j;
    }
    __syncthreads();
    for (int i = lane; i < 95; i += 64) {
        float dlt = dsrt[wid][i+1] - dsrt[wid][i];
        float dens = softplusf(0.5f * (ssrt[wid][i] + ssrt[wid][i+1]) - 1.f);
        al[wid][i] = 1.f - expf(-dens * dlt);
    }
    __syncthreads();
    if (lane == 0) {
        float T = 1.f, wsum = 0.f, dsum = 0.f;
        for (int i = 0; i < 95; ++i) {
            float a = al[wid][i];
            float wloc = a * T;
            T *= 1.f - a + 1e-10f;
            al[wid][i] = wloc;
            wsum += wloc;
            dsum += wloc * 0.5f * (dsrt[wid][i] + dsrt[wid][i+1]);
        }
        float depth = dsum / wsum;
        if (isnan(depth)) depth = INFINITY;   // nan_to_num(nan=inf)
        float gmn = __uint_as_float(minmax[0]);
        float gmx = __uint_as_float(minmax[1]);
        depth = fminf(fmaxf(depth, gmn), gmx);
        out[262144 + ray] = depth;   // depth_final
        out[270336 + ray] = wsum;    // weights.sum(2)
        out[278528 + ray] = T;       // visibility
    }
    __syncthreads();
    // rgb: 32 channels x 2 halves of the i-range
    int k = lane & 31, half = lane >> 5;
    int i0 = half * 48, i1 = half ? 95 : 48;
    const float* rc = rgb_c + (size_t)ray * 48 * 32;
    const float* rf = rgb_f + (size_t)ray * 48 * 32;
    float acc = 0.f;
    int j0 = perm[wid][i0];
    float cur = (j0 < 48) ? rc[j0*32 + k] : rf[(j0-48)*32 + k];
    for (int i = i0; i < i1; ++i) {
        int jn = perm[wid][i+1];
        float nxt = (jn < 48) ? rc[jn*32 + k] : rf[(jn-48)*32 + k];
        acc += al[wid][i] * (cur + nxt);
        cur = nxt;
    }
    acc *= 0.5f;
    acc += __shfl_xor(acc, 32);
    if (half == 0) out[(size_t)ray * 32 + k] = acc * 2.f - 1.f;
}

// ---------------------------------------------------------------------------
extern "C" void kernel_launch(void* const* d_in, const int* in_sizes, int n_in,
                              void* d_out, int out_size, void* d_ws, size_t ws_size,
                              hipStream_t stream) {
    const float* planes      = (const float*)d_in[0];
    const float* origins     = (const float*)d_in[1];
    const float* dirs        = (const float*)d_in[2];
    const float* w1          = (const float*)d_in[3];
    const float* b1          = (const float*)d_in[4];
    const float* w2          = (const float*)d_in[5];
    const float* b2          = (const float*)d_in[6];
    const float* noise_strat = (const float*)d_in[7];
    const float* noise_imp   = (const float*)d_in[8];
    float* out = (float*)d_out;
    float* ws  = (float*)d_ws;

    float* planesT = ws + OFF_PLANEST;
    float* depth_c = ws + OFF_DEPTH_C;
    float* sigma_c = ws + OFF_SIGMA_C;
    float* rgb_c   = ws + OFF_RGB_C;
    float* depth_f = ws + OFF_DEPTH_F;
    float* sigma_f = ws + OFF_SIGMA_F;
    float* rgb_f   = ws + OFF_RGB_F;
    unsigned int* minmax = (unsigned int*)(ws + OFF_MINMAX);

    hipMemsetAsync(minmax,     0xFF, 4, stream);  // uint max -> atomicMin target
    hipMemsetAsync(minmax + 1, 0x00, 4, stream);  // 0 -> atomicMax target

    transpose_planes<<<6144, 256, 0, stream>>>(planes, planesT);
    coarse_depths<<<NSAMP/256, 256, 0, stream>>>(noise_strat, depth_c);
    sample_mlp<<<NSAMP/256, 256, 0, stream>>>(planesT, depth_c, origins, dirs,
                                              w1, b1, w2, b2, sigma_c, rgb_c);
    importance_kernel<<<NRAY/64, 64, 0, stream>>>(depth_c, sigma_c, noise_imp,
                                                  depth_f, minmax);
    sample_mlp<<<NSAMP/256, 256, 0, stream>>>(planesT, depth_f, origins, dirs,
                                              w1, b1, w2, b2, sigma_f, rgb_f);
    final_march<<<NRAY/4, 256, 0, stream>>>(depth_c, sigma_c, rgb_c,
                                            depth_f, sigma_f, rgb_f, minmax, out);
}

// Round 3
// 525.059 us; speedup vs baseline: 1.0315x; 1.0315x over previous
//
#include <hip/hip_runtime.h>
#include <math.h>

// Problem constants
#define BB 2
#define RR 4096
#define NRAY (BB*RR)            // 8192
#define SC 48
#define NSAMP (NRAY*SC)         // 393216
#define CF 32
#define HID 64
#define ODIM 33                 // 1 sigma + 32 rgb
#define PRES 256
#define PLANE_HW (PRES*PRES)    // 65536
#define RAY_START 0.1f
#define RAY_END 2.0f
#define DELTA ((RAY_END-RAY_START)/(SC-1))

// workspace layout (in floats)
#define OFF_PLANEST  ((size_t)0)                        // 2*3*65536*32 = 12582912
#define OFF_DEPTH_C  ((size_t)12582912)                 // 393216
#define OFF_SIGMA_C  (OFF_DEPTH_C + 393216)             // 393216
#define OFF_RGB_C    (OFF_SIGMA_C + 393216)             // 12582912
#define OFF_DEPTH_F  (OFF_RGB_C + 12582912)             // 393216
#define OFF_SIGMA_F  (OFF_DEPTH_F + 393216)             // 393216
#define OFF_RGB_F    (OFF_SIGMA_F + 393216)             // 12582912
#define OFF_MINMAX   (OFF_RGB_F + 12582912)             // 2 uints

typedef __attribute__((ext_vector_type(8))) short bf8_t;   // 8 bf16 (4 VGPR)
typedef __attribute__((ext_vector_type(4))) float f4_t;    // MFMA acc

#define FEAT_STRIDE 40   // ushorts per feat row (32 + 8 pad) = 80 B
#define H_STRIDE    72   // ushorts per h row (64 + 8 pad) = 144 B; o reuses as 36 floats

__device__ __forceinline__ float softplusf(float x) {
    return fmaxf(x, 0.f) + log1pf(expf(-fabsf(x)));
}
__device__ __forceinline__ unsigned short f2bf(float f) {
    union { float f; unsigned int u; } v; v.f = f;
    unsigned int r = v.u + 0x7fffu + ((v.u >> 16) & 1u);   // RNE
    return (unsigned short)(r >> 16);
}
__device__ __forceinline__ unsigned int pack2(float lo, float hi) {
    return (unsigned int)f2bf(lo) | ((unsigned int)f2bf(hi) << 16);
}

// ---------------------------------------------------------------------------
// Kernel 1: transpose planes (B,3,C,H,W) -> (B,3,H,W,C); also init minmax.
__global__ __launch_bounds__(256) void transpose_planes(
    const float* __restrict__ in, float* __restrict__ out,
    unsigned int* __restrict__ minmax)
{
    if (blockIdx.x == 0 && threadIdx.x == 0) {
        minmax[0] = 0xFFFFFFFFu;   // atomicMin target (positive-float uint order)
        minmax[1] = 0u;            // atomicMax target
    }
    __shared__ float tile[32][65];
    int bid = blockIdx.x;
    int xt = bid & 3;
    int y  = (bid >> 2) & 255;
    int pp = bid >> 10;          // b*3+p in [0,6)
    int tx = threadIdx.x & 63;
    int tc = threadIdx.x >> 6;   // 0..3
    const float* src = in + (size_t)pp * 32 * PLANE_HW + (size_t)y * PRES + (size_t)xt * 64;
    #pragma unroll
    for (int i = 0; i < 8; ++i) {
        int c = i * 4 + tc;
        tile[c][tx] = src[(size_t)c * PLANE_HW + tx];
    }
    __syncthreads();
    float* dst = out + ((size_t)pp * PLANE_HW + (size_t)y * PRES + (size_t)xt * 64) * 32;
    int c2 = threadIdx.x & 31;
    int x2 = threadIdx.x >> 5;   // 0..7
    #pragma unroll
    for (int i = 0; i < 8; ++i) {
        int x = i * 8 + x2;
        dst[(size_t)x * 32 + c2] = tile[c2][x];
    }
}

// ---------------------------------------------------------------------------
// Kernel 2: gather tri-plane features + MFMA MLP (bf16 in, fp32 acc).
// 256 threads = 4 independent waves; wave w owns samples [blk*256+w*64, +64).
// No __syncthreads: all LDS traffic is same-wave.
__global__ __launch_bounds__(256) void sample_mlp(
    const float* __restrict__ planesT,
    const float* __restrict__ depths_in,   // fine pass
    const float* __restrict__ noise,       // coarse pass
    float* __restrict__ depth_out,         // coarse pass
    const float* __restrict__ origins,
    const float* __restrict__ dirs,
    const float* __restrict__ w1, const float* __restrict__ b1,
    const float* __restrict__ w2, const float* __restrict__ b2,
    float* __restrict__ sigma_out, float* __restrict__ rgb_out,
    int coarse)
{
    __shared__ __align__(16) unsigned short lds_feat[4][64 * FEAT_STRIDE]; // 20480 B
    __shared__ __align__(16) unsigned short lds_h[4][64 * H_STRIDE];       // 36864 B (reused for o as fp32)

    int tid = threadIdx.x;
    int wave = tid >> 6, lane = tid & 63;
    int quad = lane >> 4, l15 = lane & 15;
    int gid = blockIdx.x * 256 + tid;
    int ray = gid / SC;
    int b = ray >> 12;

    // ---- depth (coarse pass computes + persists it) ----
    float depth;
    if (coarse) {
        int s = gid - ray * SC;
        depth = RAY_START + (float)s * DELTA + noise[gid] * DELTA;
        depth_out[gid] = depth;
    } else {
        depth = depths_in[gid];
    }

    // ---- weight fragments ----
    // GEMM1': hT = w1T @ featT.  A1[mt]: lane holds w1T[16mt+l15][8q+j] = w1[(8q+j)*64 + 16mt+l15]
    bf8_t a1[4];
    #pragma unroll
    for (int mt = 0; mt < 4; ++mt)
        #pragma unroll
        for (int j = 0; j < 8; ++j)
            a1[mt][j] = (short)f2bf(w1[(quad * 8 + j) * HID + mt * 16 + l15]);
    float b1v[4][4];
    #pragma unroll
    for (int mt = 0; mt < 4; ++mt)
        #pragma unroll
        for (int r = 0; r < 4; ++r)
            b1v[mt][r] = b1[mt * 16 + quad * 4 + r];

    // ---- gather 32-ch tri-plane feature for this thread's sample ----
    float ox = origins[ray*3+0], oy = origins[ray*3+1], oz = origins[ray*3+2];
    float dx = dirs[ray*3+0],    dy = dirs[ray*3+1],    dz = dirs[ray*3+2];
    float cx = (ox + depth*dx) * 0.5f;
    float cy = (oy + depth*dy) * 0.5f;
    float cz = (oz + depth*dz) * 0.5f;

    float4 feat[8];
    #pragma unroll
    for (int q = 0; q < 8; ++q) feat[q] = make_float4(0.f, 0.f, 0.f, 0.f);
    float gxs[3] = {cx, cy, cz};
    float gys[3] = {cy, cz, cx};
    #pragma unroll
    for (int p = 0; p < 3; ++p) {
        float x = gxs[p] * 128.f + 127.5f;
        float y = gys[p] * 128.f + 127.5f;
        float x0f = floorf(x), y0f = floorf(y);
        float wx1 = x - x0f, wy1 = y - y0f;
        int x0 = (int)x0f, y0 = (int)y0f;
        const float4* base = (const float4*)(planesT + (size_t)(b*3+p) * PLANE_HW * 32);
        #pragma unroll
        for (int dyi = 0; dyi < 2; ++dyi) {
            int yi = y0 + dyi;
            if (yi < 0 || yi > 255) continue;
            float wy = dyi ? wy1 : (1.f - wy1);
            #pragma unroll
            for (int dxi = 0; dxi < 2; ++dxi) {
                int xi = x0 + dxi;
                if (xi < 0 || xi > 255) continue;
                float w = wy * (dxi ? wx1 : (1.f - wx1));
                const float4* tp = base + ((size_t)(yi << 8) + xi) * 8;
                #pragma unroll
                for (int q = 0; q < 8; ++q) {
                    float4 v = tp[q];
                    feat[q].x = fmaf(w, v.x, feat[q].x);
                    feat[q].y = fmaf(w, v.y, feat[q].y);
                    feat[q].z = fmaf(w, v.z, feat[q].z);
                    feat[q].w = fmaf(w, v.w, feat[q].w);
                }
            }
        }
    }
    // mean over 3 planes -> bf16 -> LDS feat row
    const float inv3 = 1.f / 3.f;
    unsigned short* frow = &lds_feat[wave][lane * FEAT_STRIDE];
    #pragma unroll
    for (int q = 0; q < 4; ++q) {
        uint4 u;
        u.x = pack2(feat[q*2].x * inv3,   feat[q*2].y * inv3);
        u.y = pack2(feat[q*2].z * inv3,   feat[q*2].w * inv3);
        u.z = pack2(feat[q*2+1].x * inv3, feat[q*2+1].y * inv3);
        u.w = pack2(feat[q*2+1].z * inv3, feat[q*2+1].w * inv3);
        ((uint4*)frow)[q] = u;
    }
    asm volatile("" ::: "memory");

    // ---- GEMM1': acc1[mt][nt] = w1T-tile(mt) x featT-tile(nt), K=32 ----
    f4_t acc1[4][4];
    #pragma unroll
    for (int mt = 0; mt < 4; ++mt)
        #pragma unroll
        for (int nt = 0; nt < 4; ++nt)
            acc1[mt][nt] = (f4_t)(0.f);
    bf8_t bfr[4];
    #pragma unroll
    for (int nt = 0; nt < 4; ++nt)
        bfr[nt] = *(const bf8_t*)&lds_feat[wave][(nt*16 + l15) * FEAT_STRIDE + quad * 8];
    #pragma unroll
    for (int mt = 0; mt < 4; ++mt)
        #pragma unroll
        for (int nt = 0; nt < 4; ++nt)
            acc1[mt][nt] = __builtin_amdgcn_mfma_f32_16x16x32_bf16(a1[mt], bfr[nt], acc1[mt][nt], 0, 0, 0);

    // ---- bias + softplus -> h[sample][hid] in LDS (bf16) ----
    // acc1[mt][nt][r] = h_pre[sample=16nt+l15][hid=16mt+4q+r]
    #pragma unroll
    for (int mt = 0; mt < 4; ++mt)
        #pragma unroll
        for (int nt = 0; nt < 4; ++nt) {
            f4_t v = acc1[mt][nt];
            uint2 hv;
            hv.x = pack2(softplusf(v[0] + b1v[mt][0]), softplusf(v[1] + b1v[mt][1]));
            hv.y = pack2(softplusf(v[2] + b1v[mt][2]), softplusf(v[3] + b1v[mt][3]));
            *(uint2*)&lds_h[wave][(nt*16 + l15) * H_STRIDE + mt*16 + quad*4] = hv;
        }
    asm volatile("" ::: "memory");

    // ---- GEMM2': oT = w2T(48-pad) @ hT, K=64 ----
    bf8_t a2[2][3];
    #pragma unroll
    for (int c = 0; c < 2; ++c)
        #pragma unroll
        for (int mt2 = 0; mt2 < 3; ++mt2) {
            int col = mt2 * 16 + l15;
            #pragma unroll
            for (int j = 0; j < 8; ++j) {
                int row = c * 32 + quad * 8 + j;
                a2[c][mt2][j] = (short)((col < ODIM) ? f2bf(w2[row * ODIM + col]) : 0);
            }
        }
    float b2v[3][4];
    #pragma unroll
    for (int mt2 = 0; mt2 < 3; ++mt2)
        #pragma unroll
        for (int r = 0; r < 4; ++r) {
            int n2 = mt2 * 16 + quad * 4 + r;
            b2v[mt2][r] = (n2 < ODIM) ? b2[n2] : 0.f;
        }

    f4_t acc2[3][4];
    #pragma unroll
    for (int mt2 = 0; mt2 < 3; ++mt2)
        #pragma unroll
        for (int nt = 0; nt < 4; ++nt)
            acc2[mt2][nt] = (f4_t)(0.f);
    #pragma unroll
    for (int c = 0; c < 2; ++c) {
        bf8_t bh[4];
        #pragma unroll
        for (int nt = 0; nt < 4; ++nt)
            bh[nt] = *(const bf8_t*)&lds_h[wave][(nt*16 + l15) * H_STRIDE + c*32 + quad*8];
        #pragma unroll
        for (int mt2 = 0; mt2 < 3; ++mt2)
            #pragma unroll
            for (int nt = 0; nt < 4; ++nt)
                acc2[mt2][nt] = __builtin_amdgcn_mfma_f32_16x16x32_bf16(a2[c][mt2], bh[nt], acc2[mt2][nt], 0, 0, 0);
    }
    asm volatile("" ::: "memory");

    // ---- o[sample][n2] (fp32, stride 36 floats) into reused lds_h ----
    // BUGFIX (R2): only store VALID outputs. mt2==2 covers out 32..47; out>32 are
    // pad and offsets 36..47 would alias the NEXT sample's o[0..11] (stride 36).
    // Store mt2 0,1 fully (out 0..31) and a single predicated float for out=32.
    float* obase = (float*)&lds_h[wave][0];
    #pragma unroll
    for (int mt2 = 0; mt2 < 2; ++mt2)
        #pragma unroll
        for (int nt = 0; nt < 4; ++nt) {
            f4_t v = acc2[mt2][nt];
            v[0] += b2v[mt2][0]; v[1] += b2v[mt2][1];
            v[2] += b2v[mt2][2]; v[3] += b2v[mt2][3];
            *(f4_t*)(obase + (nt*16 + l15) * 36 + mt2*16 + quad*4) = v;
        }
    if (quad == 0) {   // out index 32 lives at rows quad==0, reg r==0 of tile mt2==2
        #pragma unroll
        for (int nt = 0; nt < 4; ++nt)
            obase[(nt*16 + l15) * 36 + 32] = acc2[2][nt][0] + b2v[2][0];
    }
    asm volatile("" ::: "memory");

    // ---- readback own row, activation, coalesced stores ----
    float ov[36];
    const f4_t* orow = (const f4_t*)(obase + lane * 36);
    #pragma unroll
    for (int q = 0; q < 9; ++q) {
        f4_t t = orow[q];
        ov[q*4+0] = t[0]; ov[q*4+1] = t[1]; ov[q*4+2] = t[2]; ov[q*4+3] = t[3];
    }
    sigma_out[gid] = ov[0];
    float4* ro = (float4*)(rgb_out + (size_t)gid * 32);
    #pragma unroll
    for (int q = 0; q < 8; ++q) {
        float4 v;
        v.x = 1.002f / (1.f + expf(-ov[1 + q*4 + 0])) - 0.001f;
        v.y = 1.002f / (1.f + expf(-ov[1 + q*4 + 1])) - 0.001f;
        v.z = 1.002f / (1.f + expf(-ov[1 + q*4 + 2])) - 0.001f;
        v.w = 1.002f / (1.f + expf(-ov[1 + q*4 + 3])) - 0.001f;
        ro[q] = v;
    }
}

// ---------------------------------------------------------------------------
// Kernel 3: per-ray coarse ray-march -> weights -> inverse-CDF importance
__global__ __launch_bounds__(64) void importance_kernel(
    const float* __restrict__ depth_c, const float* __restrict__ sigma_c,
    const float* __restrict__ noise_imp, float* __restrict__ depth_f,
    unsigned int* __restrict__ minmax)
{
    __shared__ float s_w[64][SC-1];
    __shared__ float s_bins[64][SC-1];
    __shared__ float s_cdf[64][SC-2];
    int tid = threadIdx.x;
    int ray = blockIdx.x * 64 + tid;
    float* w    = s_w[tid];
    float* bins = s_bins[tid];
    float* cdf  = s_cdf[tid];

    const float* d  = depth_c + (size_t)ray * SC;
    const float* sg = sigma_c + (size_t)ray * SC;
    float d0 = d[0];
    float dprev = d0, sprev = sg[0];
    float T = 1.f;
    for (int i = 0; i < SC-1; ++i) {
        float d1 = d[i+1], s1 = sg[i+1];
        bins[i] = 0.5f * (dprev + d1);
        float dens = softplusf(0.5f * (sprev + s1) - 1.f);
        float a = 1.f - expf(-dens * (d1 - dprev));
        w[i] = a * T;
        T *= 1.f - a + 1e-10f;
        dprev = d1; sprev = s1;
    }
    float sum = 0.f;
    for (int i = 1; i <= 45; ++i) {
        float wn = 0.5f * (fmaxf(w[i-1], w[i]) + fmaxf(w[i], w[i+1])) + 0.01f + 1e-5f;
        cdf[i] = wn;
        sum += wn;
    }
    cdf[0] = 0.f;
    float cum = 0.f;
    for (int i = 1; i <= 45; ++i) { cum += cdf[i] / sum; cdf[i] = cum; }

    float fmn = 1e30f, fmx = -1e30f;
    const float* u_row = noise_imp + (size_t)ray * SC;
    float* df_row = depth_f + (size_t)ray * SC;
    for (int j = 0; j < SC; ++j) {
        float u = u_row[j];
        int inds = 0;
        for (int t = 0; t < 46; ++t) inds += (cdf[t] <= u) ? 1 : 0;
        int below = inds - 1; if (below < 0) below = 0;
        int above = inds;     if (above > 45) above = 45;
        float cb = cdf[below], ca = cdf[above];
        float bb = bins[below], ba = bins[above];
        float den = (ca - cb) < 1e-5f ? 1.f : (ca - cb);
        float s = bb + (u - cb) / den * (ba - bb);
        df_row[j] = s;
        fmn = fminf(fmn, s); fmx = fmaxf(fmx, s);
    }
    fmn = fminf(fmn, d0);
    fmx = fmaxf(fmx, dprev);
    atomicMin(minmax + 0, __float_as_uint(fmn));
    atomicMax(minmax + 1, __float_as_uint(fmx));
}

// ---------------------------------------------------------------------------
// Kernel 4: merge coarse+fine (stable rank sort of 96), final ray-march.
__global__ __launch_bounds__(256) void final_march(
    const float* __restrict__ depth_c, const float* __restrict__ sigma_c,
    const float* __restrict__ rgb_c,
    const float* __restrict__ depth_f, const float* __restrict__ sigma_f,
    const float* __restrict__ rgb_f,
    const unsigned int* __restrict__ minmax,
    float* __restrict__ out)
{
    __shared__ float dall[4][96];
    __shared__ float sall[4][96];
    __shared__ float dsrt[4][96];
    __shared__ float ssrt[4][96];
    __shared__ int   perm[4][96];
    __shared__ float al[4][96];

    int wid = threadIdx.x >> 6, lane = threadIdx.x & 63;
    int ray = blockIdx.x * 4 + wid;

    for (int j = lane; j < 96; j += 64) {
        float dv, sv;
        if (j < 48) { dv = depth_c[(size_t)ray*48 + j]; sv = sigma_c[(size_t)ray*48 + j]; }
        else        { dv = depth_f[(size_t)ray*48 + j-48]; sv = sigma_f[(size_t)ray*48 + j-48]; }
        dall[wid][j] = dv; sall[wid][j] = sv;
    }
    __syncthreads();
    for (int j = lane; j < 96; j += 64) {
        float dj = dall[wid][j];
        int rank = 0;
        for (int k = 0; k < 96; ++k) {
            float dk = dall[wid][k];
            rank += (dk < dj || (dk == dj && k < j)) ? 1 : 0;
        }
        dsrt[wid][rank] = dj;
        ssrt[wid][rank] = sall[wid][j];
        perm[wid][rank] = j;
    }
    __syncthreads();
    for (int i = lane; i < 95; i += 64) {
        float dlt = dsrt[wid][i+1] - dsrt[wid][i];
        float dens = softplusf(0.5f * (ssrt[wid][i] + ssrt[wid][i+1]) - 1.f);
        al[wid][i] = 1.f - expf(-dens * dlt);
    }
    __syncthreads();
    if (lane == 0) {
        float T = 1.f, wsum = 0.f, dsum = 0.f;
        for (int i = 0; i < 95; ++i) {
            float a = al[wid][i];
            float wloc = a * T;
            T *= 1.f - a + 1e-10f;
            al[wid][i] = wloc;
            wsum += wloc;
            dsum += wloc * 0.5f * (dsrt[wid][i] + dsrt[wid][i+1]);
        }
        float depth = dsum / wsum;
        if (isnan(depth)) depth = INFINITY;
        float gmn = __uint_as_float(minmax[0]);
        float gmx = __uint_as_float(minmax[1]);
        depth = fminf(fmaxf(depth, gmn), gmx);
        out[262144 + ray] = depth;
        out[270336 + ray] = wsum;
        out[278528 + ray] = T;
    }
    __syncthreads();
    int k = lane & 31, half = lane >> 5;
    int i0 = half * 48, i1 = half ? 95 : 48;
    const float* rc = rgb_c + (size_t)ray * 48 * 32;
    const float* rf = rgb_f + (size_t)ray * 48 * 32;
    float acc = 0.f;
    int j0 = perm[wid][i0];
    float cur = (j0 < 48) ? rc[j0*32 + k] : rf[(j0-48)*32 + k];
    for (int i = i0; i < i1; ++i) {
        int jn = perm[wid][i+1];
        float nxt = (jn < 48) ? rc[jn*32 + k] : rf[(jn-48)*32 + k];
        acc += al[wid][i] * (cur + nxt);
        cur = nxt;
    }
    acc *= 0.5f;
    acc += __shfl_xor(acc, 32);
    if (half == 0) out[(size_t)ray * 32 + k] = acc * 2.f - 1.f;
}

// ---------------------------------------------------------------------------
extern "C" void kernel_launch(void* const* d_in, const int* in_sizes, int n_in,
                              void* d_out, int out_size, void* d_ws, size_t ws_size,
                              hipStream_t stream) {
    const float* planes      = (const float*)d_in[0];
    const float* origins     = (const float*)d_in[1];
    const float* dirs        = (const float*)d_in[2];
    const float* w1          = (const float*)d_in[3];
    const float* b1          = (const float*)d_in[4];
    const float* w2          = (const float*)d_in[5];
    const float* b2          = (const float*)d_in[6];
    const float* noise_strat = (const float*)d_in[7];
    const float* noise_imp   = (const float*)d_in[8];
    float* out = (float*)d_out;
    float* ws  = (float*)d_ws;

    float* planesT = ws + OFF_PLANEST;
    float* depth_c = ws + OFF_DEPTH_C;
    float* sigma_c = ws + OFF_SIGMA_C;
    float* rgb_c   = ws + OFF_RGB_C;
    float* depth_f = ws + OFF_DEPTH_F;
    float* sigma_f = ws + OFF_SIGMA_F;
    float* rgb_f   = ws + OFF_RGB_F;
    unsigned int* minmax = (unsigned int*)(ws + OFF_MINMAX);

    transpose_planes<<<6144, 256, 0, stream>>>(planes, planesT, minmax);
    sample_mlp<<<NSAMP/256, 256, 0, stream>>>(planesT, nullptr, noise_strat, depth_c,
                                              origins, dirs, w1, b1, w2, b2,
                                              sigma_c, rgb_c, 1);
    importance_kernel<<<NRAY/64, 64, 0, stream>>>(depth_c, sigma_c, noise_imp,
                                                  depth_f, minmax);
    sample_mlp<<<NSAMP/256, 256, 0, stream>>>(planesT, depth_f, nullptr, nullptr,
                                              origins, dirs, w1, b1, w2, b2,
                                              sigma_f, rgb_f, 0);
    final_march<<<NRAY/4, 256, 0, stream>>>(depth_c, sigma_c, rgb_c,
                                            depth_f, sigma_f, rgb_f, minmax, out);
}